// Round 13
// baseline (1044.921 us; speedup 1.0000x reference)
//
#include <hip/hip_runtime.h>

#define U_CNT 100000
#define I_CNT 50000
#define N_CNT 150000
#define NNZ_CNT 3200000
#define EMB 64

// LOCKED correctness recipe (R9/R10 passing; R11/R12 post-mortems):
//  - spmm: R10's BYTE-EXACT function. Its f32 bits depend on compiler
//    contraction choices that vary with loop structure (R12 proof). DO NOT EDIT.
//  - h pipeline: f64, R10's exact op sequence. h is RECOMPUTED in apply
//    (identical source) instead of stored -> kills the 154 MB/layer f64
//    round-trip. Stats-side jitter from dual computation ~1e-21 (harmless;
//    R11/R12 proved 1e-14-scale f64-path changes don't flip).
//  - finalize folded into apply; stats double-buffered (R11-proven harmless).

__global__ void init_ego_kernel(const float* __restrict__ ue, const float* __restrict__ ie,
                                float* __restrict__ ego) {
  const int total = N_CNT * EMB, ucnt = U_CNT * EMB;
  for (int i = blockIdx.x * blockDim.x + threadIdx.x; i < total; i += gridDim.x * blockDim.x)
    ego[i] = (i < ucnt) ? ue[i] : ie[i - ucnt];
}

__global__ void build_row_ptr_kernel(const int* __restrict__ rows, int* __restrict__ rp) {
  int r = blockIdx.x * blockDim.x + threadIdx.x;
  if (r > N_CNT) return;
  int lo = 0, hi = NNZ_CNT;
  while (lo < hi) { int mid = (lo + hi) >> 1; if (rows[mid] < r) lo = mid + 1; else hi = mid; }
  rp[r] = lo;
}

__global__ void zero_stats_kernel(double* __restrict__ stats) {
  stats[threadIdx.x] = 0.0;
  stats[256 + threadIdx.x] = 0.0;  // both buffers
}

// ===== R10's spmm, BYTE-EXACT — do not modify (codegen-bit-locked) =====
__global__ __launch_bounds__(256) void spmm_kernel(const float* __restrict__ x, float* __restrict__ y,
                            const int* __restrict__ rp, const int* __restrict__ cols,
                            const float* __restrict__ vals) {
  const int wave = threadIdx.x >> 6, lane = threadIdx.x & 63;
  const int row = blockIdx.x * 4 + wave;
  if (row >= N_CNT) return;
  const int e0 = rp[row], e1 = rp[row + 1];
  float acc = 0.f;
  int e = e0;
  const int nmain = e0 + ((e1 - e0) & ~7);
  for (; e < nmain; e += 8) {
    float xv[8], vv[8];
    #pragma unroll
    for (int j = 0; j < 8; ++j) {
      const int c = cols[e + j];          // independent loads -> 8 outstanding
      vv[j] = vals[e + j];
      xv[j] = x[(size_t)c * EMB + lane];
    }
    #pragma unroll
    for (int j = 0; j < 8; ++j)           // sequential adds, original order
      acc = __fadd_rn(acc, __fmul_rn(vv[j], xv[j]));
  }
  for (; e < e1; ++e) {
    const int c = cols[e];
    acc = __fadd_rn(acc, __fmul_rn(vals[e], x[(size_t)c * EMB + lane]));
  }
  y[(size_t)row * EMB + lane] = acc;
}
// ===== end locked spmm =====

#define GU 512
#define GI 256

// R10's gemv op sequence (f32 LDS staging, in-loop converts, single f64 fma
// chain), WITHOUT the h store: accumulates per-column sum/sumsq only.
__global__ __launch_bounds__(256) void stats_kernel(const float* __restrict__ y,
                                  const float* __restrict__ Wu, const float* __restrict__ bu,
                                  const float* __restrict__ Wi, const float* __restrict__ bi,
                                  double* __restrict__ stats) {
  __shared__ float ysh[4][EMB];
  __shared__ double red[4][EMB];
  const int wave = threadIdx.x >> 6, lane = threadIdx.x & 63;
  const bool isU = blockIdx.x < GU;
  const int blk = isU ? blockIdx.x : blockIdx.x - GU;
  const int nblk = isU ? GU : GI;
  const int nrows = isU ? U_CNT : I_CNT;
  const float* Wf = isU ? Wu : Wi;
  const float* bf = isU ? bu : bi;
  const float* yp = isU ? y : (y + (size_t)U_CNT * EMB);
  double* sum_out = stats + (isU ? 0 : 128);
  double* sq_out = sum_out + 64;

  float w[EMB];
  #pragma unroll
  for (int k = 0; k < EMB; k += 4) {
    float4 t = *(const float4*)&Wf[lane * EMB + k];
    w[k] = t.x; w[k+1] = t.y; w[k+2] = t.z; w[k+3] = t.w;
  }
  const double bj = (double)bf[lane];
  double s = 0.0, q = 0.0;
  for (int r = blk * 4 + wave; r < nrows; r += nblk * 4) {
    ysh[wave][lane] = yp[(size_t)r * EMB + lane];
    double acc = 0.0;
    #pragma unroll
    for (int k = 0; k < EMB; ++k) acc = fma((double)ysh[wave][k], (double)w[k], acc);
    double h0 = acc + bj;
    h0 = (h0 >= 0.0) ? h0 : 0.01 * h0;
    s += h0;
    q = fma(h0, h0, q);
  }
  red[wave][lane] = s;
  __syncthreads();
  if (wave == 0)
    atomicAdd(&sum_out[lane], red[0][lane] + red[1][lane] + red[2][lane] + red[3][lane]);
  __syncthreads();
  red[wave][lane] = q;
  __syncthreads();
  if (wave == 0)
    atomicAdd(&sq_out[lane], red[0][lane] + red[1][lane] + red[2][lane] + red[3][lane]);
}

// apply: recomputes h with the IDENTICAL op sequence (f32 LDS + in-loop
// converts + single f64 fma chain); mu/R derived inline (R11-proven);
// hn/nrm/noise/en = R10's exact apply math. Block 0 zeroes next stats buffer.
__global__ __launch_bounds__(256) void apply_kernel(const float* __restrict__ y,
                             float* __restrict__ ego, float* __restrict__ out_final,
                             float* __restrict__ out_cl,
                             const double* __restrict__ stats, double* __restrict__ stats_next,
                             const float* __restrict__ Wu, const float* __restrict__ bu,
                             const float* __restrict__ gu, const float* __restrict__ btu,
                             const float* __restrict__ Wi, const float* __restrict__ bi,
                             const float* __restrict__ gi, const float* __restrict__ bti,
                             int layer) {
  __shared__ float ysh[4][EMB];
  const int wave = threadIdx.x >> 6, lane = threadIdx.x & 63;
  if (blockIdx.x == 0) stats_next[threadIdx.x] = 0.0;
  const bool isU = blockIdx.x < GU;
  const int blk = isU ? blockIdx.x : blockIdx.x - GU;
  const int nblk = isU ? GU : GI;
  const int nrows = isU ? U_CNT : I_CNT;
  const size_t off = isU ? 0 : (size_t)U_CNT * EMB;
  const float* Wf = isU ? Wu : Wi;
  const float* bf = isU ? bu : bi;

  float w[EMB];
  #pragma unroll
  for (int k = 0; k < EMB; k += 4) {
    float4 t = *(const float4*)&Wf[lane * EMB + k];
    w[k] = t.x; w[k+1] = t.y; w[k+2] = t.z; w[k+3] = t.w;
  }
  const double bj = (double)bf[lane];
  const double cnt = isU ? (double)U_CNT : (double)I_CNT;
  const double S = stats[(isU ? 0 : 128) + lane];
  const double Q = stats[(isU ? 0 : 128) + 64 + lane];
  const double muj = S / cnt;
  double var = Q / cnt - muj * muj;
  if (var < 0.0) var = 0.0;
  const double Rj = 1.0 / sqrt(var + 1e-5);
  const double gj = (double)(isU ? gu[lane] : gi[lane]);
  const double btj = (double)(isU ? btu[lane] : bti[lane]);

  for (int r = blk * 4 + wave; r < nrows; r += nblk * 4) {
    const size_t o = off + (size_t)r * EMB + lane;
    const float yv = y[o];
    ysh[wave][lane] = yv;
    double acc = 0.0;
    #pragma unroll
    for (int k = 0; k < EMB; ++k) acc = fma((double)ysh[wave][k], (double)w[k], acc);
    double h0 = acc + bj;
    h0 = (h0 >= 0.0) ? h0 : 0.01 * h0;
    const double hn = ((h0 - muj) * Rj) * gj + btj;
    double ss = hn * hn;
    #pragma unroll
    for (int sh = 32; sh > 0; sh >>= 1) ss += __shfl_xor(ss, sh, 64);
    double nrm = sqrt(ss);
    if (nrm < 1e-12) nrm = 1e-12;
    const float noise = (float)(hn / nrm);
    const float sgn = (yv > 0.f) ? 1.f : ((yv < 0.f) ? -1.f : 0.f);
    const float t2 = __fmul_rn(__fmul_rn(sgn, noise), 0.1f);
    const float en = __fadd_rn(yv, t2);
    ego[o] = en;
    if (layer == 0) { out_final[o] = en; out_cl[o] = en; }
    else if (layer == 1) { out_final[o] = __fadd_rn(out_final[o], en); }
    else { out_final[o] = __fdiv_rn(__fadd_rn(out_final[o], en), 3.0f); }
  }
}

extern "C" void kernel_launch(void* const* d_in, const int* in_sizes, int n_in,
                              void* d_out, int out_size, void* d_ws, size_t ws_size,
                              hipStream_t stream) {
  const float* user_emb = (const float*)d_in[0];
  const float* item_emb = (const float*)d_in[1];
  const int* adj_rows = (const int*)d_in[2];
  const int* adj_cols = (const int*)d_in[3];
  const float* adj_vals = (const float*)d_in[4];
  const float* Wu = (const float*)d_in[5];
  const float* bu = (const float*)d_in[6];
  const float* gu = (const float*)d_in[7];
  const float* btu = (const float*)d_in[8];
  const float* Wi = (const float*)d_in[9];
  const float* bi = (const float*)d_in[10];
  const float* gi = (const float*)d_in[11];
  const float* bti = (const float*)d_in[12];
  float* out = (float*)d_out;

  float* ego = (float*)d_ws;                            // [N,64] f32
  float* y = ego + (size_t)N_CNT * EMB;                 // [N,64] f32
  double* stats = (double*)(y + (size_t)N_CNT * EMB);   // 2 x 256 f64 (double-buffered)
  int* rp = (int*)(stats + 512);                        // [N+1]

  float* out_final = out;                               // final [N,64] flat f32
  float* out_cl = out + (size_t)N_CNT * EMB;            // emb_cl [N,64] flat f32

  init_ego_kernel<<<2048, 256, 0, stream>>>(user_emb, item_emb, ego);
  build_row_ptr_kernel<<<(N_CNT + 1 + 255) / 256, 256, 0, stream>>>(adj_rows, rp);
  zero_stats_kernel<<<1, 256, 0, stream>>>(stats);

  for (int layer = 0; layer < 3; ++layer) {
    double* stats_cur = stats + (layer & 1) * 256;
    double* stats_next = stats + ((layer + 1) & 1) * 256;
    spmm_kernel<<<(N_CNT + 3) / 4, 256, 0, stream>>>(ego, y, rp, adj_cols, adj_vals);
    stats_kernel<<<GU + GI, 256, 0, stream>>>(y, Wu, bu, Wi, bi, stats_cur);
    apply_kernel<<<GU + GI, 256, 0, stream>>>(y, ego, out_final, out_cl,
                                              stats_cur, stats_next,
                                              Wu, bu, gu, btu, Wi, bi, gi, bti, layer);
  }
}